// Round 1
// baseline (20661.748 us; speedup 1.0000x reference)
//
#include <hip/hip_runtime.h>
#include <hip/hip_bf16.h>

#define BB 32
#define TT 1000
#define HH 512
#define H2 1024
#define H4 2048
#define VV 10000
#define LL 100
#define NCH 8
#define TCHUNK 125

typedef unsigned short u16;
typedef unsigned int u32;

__device__ __forceinline__ float bf2f(u16 s){ return __uint_as_float(((u32)s)<<16); }
__device__ __forceinline__ u16 f2bf(float f){
  u32 u = __float_as_uint(f);
  u32 r = (u + 0x7fffu + ((u>>16)&1u)) >> 16;
  return (u16)r;
}
__device__ __forceinline__ float fast_tanh(float x){
  float e = __expf(2.0f*x);
  return 1.0f - 2.0f/(e+1.0f);
}
__device__ __forceinline__ float sigm(float x){ return 0.5f*fast_tanh(0.5f*x)+0.5f; }

__global__ __launch_bounds__(256) void k_zero(float4* __restrict__ p){
  p[blockIdx.x*256 + threadIdx.x] = make_float4(0.f,0.f,0.f,0.f);
}

// ---------- one-time: h_proj = h @ W_h_att + b_att  (fp32 GEMM -> bf16 store) ----------
__global__ __launch_bounds__(256) void k_hproj(const float* __restrict__ h,
    const float* __restrict__ W, const float* __restrict__ bias,
    u16* __restrict__ hp)
{
  __shared__ float sA[16][68];
  __shared__ float sB[16][68];
  const int m0 = blockIdx.x * 64;
  const int n0 = blockIdx.y * 64;
  const int tid = threadIdx.x;
  const int trow = tid >> 4, tcol = tid & 15;
  const int a_row = tid & 63, a_k = (tid >> 6) * 4;
  const int b_row = tid >> 4, b_n = (tid & 15) * 4;
  float acc[4][4];
  #pragma unroll
  for (int i=0;i<4;i++)
    #pragma unroll
    for (int j=0;j<4;j++) acc[i][j]=0.f;
  for (int k0 = 0; k0 < H2; k0 += 16) {
    float4 av = *(const float4*)(h + (size_t)(m0 + a_row)*H2 + k0 + a_k);
    sA[a_k+0][a_row]=av.x; sA[a_k+1][a_row]=av.y; sA[a_k+2][a_row]=av.z; sA[a_k+3][a_row]=av.w;
    *(float4*)(&sB[b_row][b_n]) = *(const float4*)(W + (size_t)(k0 + b_row)*HH + n0 + b_n);
    __syncthreads();
    #pragma unroll
    for (int k=0;k<16;k++){
      float a0=sA[k][trow*4+0], a1=sA[k][trow*4+1], a2=sA[k][trow*4+2], a3=sA[k][trow*4+3];
      float c0=sB[k][tcol*4+0], c1=sB[k][tcol*4+1], c2=sB[k][tcol*4+2], c3=sB[k][tcol*4+3];
      acc[0][0]+=a0*c0; acc[0][1]+=a0*c1; acc[0][2]+=a0*c2; acc[0][3]+=a0*c3;
      acc[1][0]+=a1*c0; acc[1][1]+=a1*c1; acc[1][2]+=a1*c2; acc[1][3]+=a1*c3;
      acc[2][0]+=a2*c0; acc[2][1]+=a2*c1; acc[2][2]+=a2*c2; acc[2][3]+=a2*c3;
      acc[3][0]+=a3*c0; acc[3][1]+=a3*c1; acc[3][2]+=a3*c2; acc[3][3]+=a3*c3;
    }
    __syncthreads();
  }
  #pragma unroll
  for (int i=0;i<4;i++){
    int row = m0 + trow*4 + i;
    ushort4 o;
    o.x = f2bf(acc[i][0] + bias[n0+tcol*4+0]);
    o.y = f2bf(acc[i][1] + bias[n0+tcol*4+1]);
    o.z = f2bf(acc[i][2] + bias[n0+tcol*4+2]);
    o.w = f2bf(acc[i][3] + bias[n0+tcol*4+3]);
    *(ushort4*)(hp + (size_t)row*HH + n0 + tcol*4) = o;
  }
}

// ---------- final: out = zall[3200,512] @ W_yy[512,10000] + b_yy ----------
__global__ __launch_bounds__(256) void k_ybig(const float* __restrict__ zall,
    const float* __restrict__ W, const float* __restrict__ bias,
    float* __restrict__ out)
{
  __shared__ float sA[16][68];
  __shared__ float sB[16][68];
  const int m0 = blockIdx.x * 64;
  const int n0 = blockIdx.y * 64;
  const int tid = threadIdx.x;
  const int trow = tid >> 4, tcol = tid & 15;
  const int a_row = tid & 63, a_k = (tid >> 6) * 4;
  const int b_row = tid >> 4, b_n = (tid & 15) * 4;
  float acc[4][4];
  #pragma unroll
  for (int i=0;i<4;i++)
    #pragma unroll
    for (int j=0;j<4;j++) acc[i][j]=0.f;
  for (int k0 = 0; k0 < HH; k0 += 16) {
    float4 av = *(const float4*)(zall + (size_t)(m0 + a_row)*HH + k0 + a_k);
    sA[a_k+0][a_row]=av.x; sA[a_k+1][a_row]=av.y; sA[a_k+2][a_row]=av.z; sA[a_k+3][a_row]=av.w;
    float4 bv = make_float4(0.f,0.f,0.f,0.f);
    if (n0 + b_n < VV) bv = *(const float4*)(W + (size_t)(k0 + b_row)*VV + n0 + b_n);
    *(float4*)(&sB[b_row][b_n]) = bv;
    __syncthreads();
    #pragma unroll
    for (int k=0;k<16;k++){
      float a0=sA[k][trow*4+0], a1=sA[k][trow*4+1], a2=sA[k][trow*4+2], a3=sA[k][trow*4+3];
      float c0=sB[k][tcol*4+0], c1=sB[k][tcol*4+1], c2=sB[k][tcol*4+2], c3=sB[k][tcol*4+3];
      acc[0][0]+=a0*c0; acc[0][1]+=a0*c1; acc[0][2]+=a0*c2; acc[0][3]+=a0*c3;
      acc[1][0]+=a1*c0; acc[1][1]+=a1*c1; acc[1][2]+=a1*c2; acc[1][3]+=a1*c3;
      acc[2][0]+=a2*c0; acc[2][1]+=a2*c1; acc[2][2]+=a2*c2; acc[2][3]+=a2*c3;
      acc[3][0]+=a3*c0; acc[3][1]+=a3*c1; acc[3][2]+=a3*c2; acc[3][3]+=a3*c3;
    }
    __syncthreads();
  }
  #pragma unroll
  for (int i=0;i<4;i++){
    int r = m0 + trow*4 + i;
    int l = r >> 5, b = r & 31;
    #pragma unroll
    for (int j=0;j<4;j++){
      int col = n0 + tcol*4 + j;
      if (col < VV) out[((size_t)b*LL + l)*VV + col] = acc[i][j] + bias[col];
    }
  }
}

// ---------- per-step attention pass: partial softmax-weighted sums ----------
// no-max softmax is safe: |e| <= sum|w_att| ~ 8.2, exp() cannot overflow
__global__ __launch_bounds__(256) void k_flash(const u16* __restrict__ hp,
    const float* __restrict__ h, const float* __restrict__ proj_att,
    const float* __restrict__ w_att, const int* __restrict__ seq_lens,
    float* __restrict__ gpart, float* __restrict__ Zpart)
{
  const int b = blockIdx.y, chunk = blockIdx.x;
  const int tid = threadIdx.x, lane = tid & 63, wv = tid >> 6;
  const int len = seq_lens[b];
  const int t0 = chunk * TCHUNK;
  const int tmax = min(t0 + TCHUNK, len);
  float wa[8], sw[8];
  #pragma unroll
  for (int i=0;i<8;i++){ wa[i]=w_att[lane*8+i]; sw[i]=proj_att[b*HH+lane*8+i]; }
  float gacc[16];
  #pragma unroll
  for (int i=0;i<16;i++) gacc[i]=0.f;
  float zacc = 0.f;
  for (int t = t0 + wv; t < tmax; t += 4) {
    const uint4 hv = *(const uint4*)(hp + ((size_t)b*TT + t)*HH + lane*8);
    u32 uu[4] = {hv.x, hv.y, hv.z, hv.w};
    float p = 0.f;
    #pragma unroll
    for (int q=0;q<4;q++){
      float f0 = bf2f((u16)(uu[q] & 0xffffu));
      float f1 = bf2f((u16)(uu[q] >> 16));
      p += wa[2*q+0]*fast_tanh(f0+sw[2*q+0]);
      p += wa[2*q+1]*fast_tanh(f1+sw[2*q+1]);
    }
    #pragma unroll
    for (int off=32; off; off>>=1) p += __shfl_xor(p, off, 64);
    float wgt = __expf(p);
    zacc += wgt;
    const float4* hrow = (const float4*)(h + ((size_t)b*TT + t)*H2 + lane*16);
    #pragma unroll
    for (int q=0;q<4;q++){
      float4 x = hrow[q];
      gacc[4*q+0] += wgt*x.x; gacc[4*q+1] += wgt*x.y;
      gacc[4*q+2] += wgt*x.z; gacc[4*q+3] += wgt*x.w;
    }
  }
  __shared__ float sg[4][H2];
  __shared__ float szz[4];
  #pragma unroll
  for (int q=0;q<4;q++)
    *(float4*)(&sg[wv][lane*16+q*4]) = make_float4(gacc[4*q],gacc[4*q+1],gacc[4*q+2],gacc[4*q+3]);
  if (lane==0) szz[wv]=zacc;
  __syncthreads();
  float4 s0 = *(float4*)(&sg[0][tid*4]);
  float4 s1 = *(float4*)(&sg[1][tid*4]);
  float4 s2 = *(float4*)(&sg[2][tid*4]);
  float4 s3 = *(float4*)(&sg[3][tid*4]);
  float4 r = make_float4(s0.x+s1.x+s2.x+s3.x, s0.y+s1.y+s2.y+s3.y,
                         s0.z+s1.z+s2.z+s3.z, s0.w+s1.w+s2.w+s3.w);
  *(float4*)(gpart + ((size_t)(b*NCH+chunk))*H2 + tid*4) = r;
  if (tid==0) Zpart[b*NCH+chunk] = szz[0]+szz[1]+szz[2]+szz[3];
}

// ---------- per-step: combine g, [32,1024]@[1024,2560] -> z(tanh), rec ----------
__global__ __launch_bounds__(256) void k_step(const float* __restrict__ gpart,
    const float* __restrict__ Zpart,
    const float* __restrict__ proj_sy, const float* __restrict__ proj_sr,
    const int* __restrict__ labels, const int l,
    const float* __restrict__ W_gy, const float* __restrict__ W_gr,
    const float* __restrict__ b_gy, const float* __restrict__ b_sy,
    const float* __restrict__ b_sr, const float* __restrict__ b_gr,
    const float* __restrict__ E_yr,
    float* __restrict__ zrow, float* __restrict__ recbuf)
{
  __shared__ float sG[BB][H2];
  __shared__ float sInvZ[BB];
  const int tid = threadIdx.x;
  if (tid < BB) {
    float z = 0.f;
    #pragma unroll
    for (int c=0;c<NCH;c++) z += Zpart[tid*NCH+c];
    sInvZ[tid] = 1.f/z;
  }
  __syncthreads();
  for (int e = tid; e < BB*H2; e += 256) {
    int b = e >> 10, k = e & (H2-1);
    float s = 0.f;
    #pragma unroll
    for (int c=0;c<NCH;c++) s += gpart[((size_t)(b*NCH+c))*H2 + k];
    sG[b][k] = s * sInvZ[b];
  }
  __syncthreads();
  const int tx = tid & 63, ty = tid >> 6;
  const int j0 = blockIdx.x * 64;
  const float* Wp; int stride, col;
  if (j0 < HH) { Wp = W_gy; stride = HH; col = j0 + tx; }
  else         { Wp = W_gr; stride = H4; col = j0 - HH + tx; }
  float acc[8];
  #pragma unroll
  for (int i=0;i<8;i++) acc[i]=0.f;
  for (int k=0;k<H2;k+=4){
    float w0 = Wp[(size_t)(k+0)*stride + col];
    float w1 = Wp[(size_t)(k+1)*stride + col];
    float w2 = Wp[(size_t)(k+2)*stride + col];
    float w3 = Wp[(size_t)(k+3)*stride + col];
    #pragma unroll
    for (int bb=0;bb<8;bb++){
      float4 g = *(const float4*)(&sG[ty*8+bb][k]);
      acc[bb] += g.x*w0 + g.y*w1 + g.z*w2 + g.w*w3;
    }
  }
  if (j0 < HH) {
    const int j = col;
    const float add = b_gy[j] + b_sy[j];
    #pragma unroll
    for (int bb=0;bb<8;bb++){
      int b = ty*8+bb;
      zrow[b*HH + j] = fast_tanh(acc[bb] + proj_sy[b*HH+j] + add);
    }
  } else {
    const int q = col;
    const float add = b_sr[q] + b_gr[q];
    #pragma unroll
    for (int bb=0;bb<8;bb++){
      int b = ty*8+bb;
      int tok = labels[b*LL + l];
      recbuf[b*H4 + q] = acc[bb] + proj_sr[b*H4+q] + add + E_yr[(size_t)tok*H4 + q];
    }
  }
}

// ---------- per-step: LSTM (inline, redundant per block) + s_next projections ----------
__global__ __launch_bounds__(256) void k_proj(const float* __restrict__ recbuf,
    const float* __restrict__ c_in,
    const float* __restrict__ W_s_att, const float* __restrict__ W_sy,
    const float* __restrict__ W_sr,
    float* __restrict__ c_out,
    float* __restrict__ proj_att, float* __restrict__ proj_sy,
    float* __restrict__ proj_sr)
{
  __shared__ float sS[BB][HH];
  const int tid = threadIdx.x;
  for (int e=tid; e<BB*HH; e+=256){
    int b = e >> 9, q = e & (HH-1);
    const float* rb = recbuf + (size_t)b*H4;
    float i_ = sigm(rb[q]);
    float f_ = sigm(rb[HH+q]);
    float cg = fast_tanh(rb[H2+q]);
    float o_ = sigm(rb[1536+q]);
    float cn = f_*c_in[e] + i_*cg;
    if (blockIdx.x == 0) c_out[e] = cn;
    sS[b][q] = o_*fast_tanh(cn);
  }
  __syncthreads();
  const int tx = tid & 63, ty = tid >> 6;
  const int pj = blockIdx.x * 64;
  const float* Wp; int stride, col; float* outp; int ostride;
  if (pj < HH)      { Wp=W_s_att; stride=HH; col=pj+tx;     outp=proj_att; ostride=HH; }
  else if (pj < H2) { Wp=W_sy;    stride=HH; col=pj-HH+tx;  outp=proj_sy;  ostride=HH; }
  else              { Wp=W_sr;    stride=H4; col=pj-H2+tx;  outp=proj_sr;  ostride=H4; }
  float acc[8];
  #pragma unroll
  for (int i=0;i<8;i++) acc[i]=0.f;
  for (int k=0;k<HH;k+=4){
    float w0 = Wp[(size_t)(k+0)*stride + col];
    float w1 = Wp[(size_t)(k+1)*stride + col];
    float w2 = Wp[(size_t)(k+2)*stride + col];
    float w3 = Wp[(size_t)(k+3)*stride + col];
    #pragma unroll
    for (int bb=0;bb<8;bb++){
      float4 s4 = *(const float4*)(&sS[ty*8+bb][k]);
      acc[bb] += s4.x*w0 + s4.y*w1 + s4.z*w2 + s4.w*w3;
    }
  }
  #pragma unroll
  for (int bb=0;bb<8;bb++){
    outp[(ty*8+bb)*ostride + col] = acc[bb];
  }
}

extern "C" void kernel_launch(void* const* d_in, const int* in_sizes, int n_in,
                              void* d_out, int out_size, void* d_ws, size_t ws_size,
                              hipStream_t stream)
{
  (void)in_sizes; (void)n_in; (void)out_size; (void)ws_size;
  const float* h       = (const float*)d_in[0];
  const int*   seq     = (const int*)d_in[1];
  const int*   labels  = (const int*)d_in[2];
  const float* W_sy    = (const float*)d_in[3];
  const float* b_sy    = (const float*)d_in[4];
  const float* W_gy    = (const float*)d_in[5];
  const float* b_gy    = (const float*)d_in[6];
  const float* W_yy    = (const float*)d_in[7];
  const float* b_yy    = (const float*)d_in[8];
  const float* E_yr    = (const float*)d_in[9];
  const float* W_sr    = (const float*)d_in[10];
  const float* b_sr    = (const float*)d_in[11];
  const float* W_gr    = (const float*)d_in[12];
  const float* b_gr    = (const float*)d_in[13];
  const float* W_s_att = (const float*)d_in[14];
  const float* W_h_att = (const float*)d_in[15];
  const float* b_att   = (const float*)d_in[16];
  const float* w_att   = (const float*)d_in[17];
  float* out = (float*)d_out;

  char* w = (char*)d_ws;
  u16*   hp     = (u16*)w;   w += (size_t)BB*TT*HH*2;     // 32.77 MB
  float* gpart  = (float*)w; w += (size_t)BB*NCH*H2*4;    // 1 MB
  float* Zpart  = (float*)w; w += (size_t)BB*NCH*4;
  float* zall   = (float*)w; w += (size_t)LL*BB*HH*4;     // 6.55 MB
  float* recbuf = (float*)w; w += (size_t)BB*H4*4;        // 256 KB
  float* zerobase = (float*)w;
  float* proj_att = (float*)w; w += (size_t)BB*HH*4;
  float* proj_sy  = (float*)w; w += (size_t)BB*HH*4;
  float* proj_sr  = (float*)w; w += (size_t)BB*H4*4;
  float* cbuf     = (float*)w; w += (size_t)2*BB*HH*4;

  // one-time precompute + zero recurrent state (must re-run every call)
  k_hproj<<<dim3(500,8),256,0,stream>>>(h, W_h_att, b_att, hp);
  k_zero<<<128,256,0,stream>>>((float4*)zerobase);   // proj_att|proj_sy|proj_sr|cbuf = 131072 floats

  for (int l=0;l<LL;l++){
    k_flash<<<dim3(NCH,BB),256,0,stream>>>(hp, h, proj_att, w_att, seq, gpart, Zpart);
    k_step<<<40,256,0,stream>>>(gpart, Zpart, proj_sy, proj_sr, labels, l,
                                W_gy, W_gr, b_gy, b_sy, b_sr, b_gr, E_yr,
                                zall + (size_t)l*BB*HH, recbuf);
    const float* c_in  = cbuf + (size_t)(l&1)*BB*HH;
    float*       c_out = cbuf + (size_t)((l+1)&1)*BB*HH;
    k_proj<<<48,256,0,stream>>>(recbuf, c_in, W_s_att, W_sy, W_sr,
                                c_out, proj_att, proj_sy, proj_sr);
  }
  k_ybig<<<dim3(50,157),256,0,stream>>>(zall, W_yy, b_yy, out);
}

// Round 2
// 11323.837 us; speedup vs baseline: 1.8246x; 1.8246x over previous
//
#include <hip/hip_runtime.h>
#include <hip/hip_bf16.h>

#define BB 32
#define TT 1000
#define HH 512
#define H2 1024
#define H4 2048
#define VV 10000
#define LL 100

typedef unsigned short u16;
typedef unsigned int u32;
typedef short short8 __attribute__((ext_vector_type(8)));
typedef float f32x4 __attribute__((ext_vector_type(4)));

__device__ __forceinline__ float bf2f(u16 s){ return __uint_as_float(((u32)s)<<16); }
__device__ __forceinline__ u16 f2bf(float f){
  u32 u = __float_as_uint(f);
  u32 r = (u + 0x7fffu + ((u>>16)&1u)) >> 16;
  return (u16)r;
}
__device__ __forceinline__ float fast_tanh(float x){
  float e = __expf(2.0f*x);
  return 1.0f - 2.0f/(e+1.0f);
}
__device__ __forceinline__ float sigm(float x){ return 0.5f*fast_tanh(0.5f*x)+0.5f; }

__device__ __forceinline__ f32x4 mfma16(short8 a, short8 b, f32x4 c){
  return __builtin_amdgcn_mfma_f32_16x16x32_bf16(a, b, c, 0, 0, 0);
}

__device__ __forceinline__ void ld8(const float* __restrict__ p, float* v){
  float4 a = *(const float4*)p, b = *(const float4*)(p+4);
  v[0]=a.x; v[1]=a.y; v[2]=a.z; v[3]=a.w; v[4]=b.x; v[5]=b.y; v[6]=b.z; v[7]=b.w;
}

__global__ __launch_bounds__(256) void k_zero(float4* __restrict__ p){
  p[blockIdx.x*256 + threadIdx.x] = make_float4(0.f,0.f,0.f,0.f);
}

// convert h (fp32) -> hb (bf16), grid-stride over float4
__global__ __launch_bounds__(256) void k_cvt_h(const float4* __restrict__ src,
    ushort4* __restrict__ dst, int n4){
  for (int i = blockIdx.x*256+threadIdx.x; i < n4; i += gridDim.x*256){
    float4 v = src[i];
    ushort4 o; o.x=f2bf(v.x); o.y=f2bf(v.y); o.z=f2bf(v.z); o.w=f2bf(v.w);
    dst[i]=o;
  }
}

// pre-swizzle weights into MFMA B-fragment order: dst[nt][kt][lane][8] bf16
// element (nt,kt,l,e) = W[kt*32 + (l>>4)*8 + e][nt*16 + (l&15)], from up to 3
// concatenated column-spaces, zero-padded past n0+n1+n2.
__global__ __launch_bounds__(256) void k_swz(u16* __restrict__ dst, int NT, int KT,
    const float* s0, int n0, int ld0, const float* s1, int n1, int ld1,
    const float* s2, int n2, int ld2)
{
  int gid = blockIdx.x*256+threadIdx.x;
  int total = NT*KT*64;
  if (gid >= total) return;
  int l = gid & 63;
  int kt = (gid >> 6) % KT;
  int nt = gid / (KT*64);
  int n = nt*16 + (l & 15);
  int k = kt*32 + ((l>>4)<<3);
  const float* sp = 0; int ld=0, col=0;
  if (n < n0){ sp=s0; ld=ld0; col=n; }
  else if (n < n0+n1){ sp=s1; ld=ld1; col=n-n0; }
  else if (n < n0+n1+n2){ sp=s2; ld=ld2; col=n-n0-n1; }
  short8 v;
  #pragma unroll 8
  for (int e=0;e<8;e++){
    float f = sp ? sp[(size_t)(k+e)*ld + col] : 0.f;
    v[e] = (short)f2bf(f);
  }
  *(short8*)(dst + (size_t)gid*8) = v;
}

// one-time: hp = h @ W_h_att + b_att  (MFMA, A=fp32 h cvt on the fly) -> bf16
__global__ __launch_bounds__(256) void k_hproj(const float* __restrict__ h,
  const u16* __restrict__ WhF, const float* __restrict__ b_att, u16* __restrict__ hp)
{
  const int tid = threadIdx.x, l = tid & 63, wv = tid >> 6;
  const int wm = wv >> 1, wn = wv & 1;
  const int Mbase = blockIdx.x*128 + wm*64;   // grid.x = 250 (M = 32000)
  const int Nbase = blockIdx.y*128 + wn*64;   // grid.y = 4   (N = 512)
  const int arow = l & 15, ak = (l>>4)<<3;
  f32x4 acc[4][4] = {};
  for (int kt=0; kt<32; kt++){
    short8 a[4], b[4];
    #pragma unroll
    for (int mt=0;mt<4;mt++){
      const float* p = h + (size_t)(Mbase + mt*16 + arow)*H2 + kt*32 + ak;
      float vv[8]; ld8(p, vv);
      short8 t;
      #pragma unroll 8
      for (int e=0;e<8;e++) t[e] = (short)f2bf(vv[e]);
      a[mt]=t;
    }
    #pragma unroll
    for (int nt=0;nt<4;nt++){
      int ntg = (Nbase>>4) + nt;
      b[nt] = *(const short8*)(WhF + (((size_t)ntg*32 + kt)*64 + l)*8);
    }
    #pragma unroll
    for (int mt=0;mt<4;mt++)
      #pragma unroll
      for (int nt=0;nt<4;nt++)
        acc[mt][nt] = mfma16(a[mt], b[nt], acc[mt][nt]);
  }
  #pragma unroll
  for (int mt=0;mt<4;mt++)
    #pragma unroll
    for (int nt=0;nt<4;nt++){
      int n = Nbase + nt*16 + (l&15);
      float bias = b_att[n];
      #pragma unroll
      for (int r=0;r<4;r++){
        int row = Mbase + mt*16 + ((l>>4)<<2) + r;
        hp[(size_t)row*HH + n] = f2bf(acc[mt][nt][r] + bias);
      }
    }
}

// final: out = zF(A-frags) @ WyyF + b_yy   M=3200 N=10240(pad) K=512
__global__ __launch_bounds__(256) void k_ybig(const u16* __restrict__ zF,
  const u16* __restrict__ WyyF, const float* __restrict__ b_yy, float* __restrict__ out)
{
  const int tid=threadIdx.x, l=tid&63, wv=tid>>6;
  const int wm=wv>>1, wn=wv&1;
  const int mtB = blockIdx.x*8 + wm*4;   // grid.x = 25
  const int ntB = blockIdx.y*8 + wn*4;   // grid.y = 80
  f32x4 acc[4][4] = {};
  for (int kt=0; kt<16; kt++){
    short8 a[4], b[4];
    #pragma unroll
    for (int mt=0;mt<4;mt++)
      a[mt] = *(const short8*)(zF + (((size_t)(mtB+mt)*16 + kt)*64 + l)*8);
    #pragma unroll
    for (int nt=0;nt<4;nt++)
      b[nt] = *(const short8*)(WyyF + (((size_t)(ntB+nt)*16 + kt)*64 + l)*8);
    #pragma unroll
    for (int mt=0;mt<4;mt++)
      #pragma unroll
      for (int nt=0;nt<4;nt++)
        acc[mt][nt] = mfma16(a[mt], b[nt], acc[mt][nt]);
  }
  #pragma unroll
  for (int mt=0;mt<4;mt++)
    #pragma unroll
    for (int nt=0;nt<4;nt++){
      int n = (ntB+nt)*16 + (l&15);
      if (n < VV){
        float bias = b_yy[n];
        #pragma unroll
        for (int r=0;r<4;r++){
          int row = (mtB+mt)*16 + ((l>>4)<<2) + r;
          out[(size_t)row*VV + n] = acc[mt][nt][r] + bias;
        }
      }
    }
}

// per-step attention: no-max softmax partials (|e| <= sum|w_att| ~ 8.2)
__global__ __launch_bounds__(512) void k_flash(const u16* __restrict__ hp,
  const u16* __restrict__ hb, const float* __restrict__ proj_att,
  const float* __restrict__ w_att, const int* __restrict__ seq_lens,
  float* __restrict__ gpart, float* __restrict__ Zpart)
{
  const int b = blockIdx.y, chunk = blockIdx.x;
  const int tid = threadIdx.x, lane = tid & 63, wv = tid >> 6;
  const int len = seq_lens[b];
  const int t0 = chunk * 125;
  const int tmax = min(t0 + 125, len);
  float wa[8], sw[8];
  #pragma unroll 8
  for (int i=0;i<8;i++){ wa[i]=w_att[lane*8+i]; sw[i]=proj_att[b*HH+lane*8+i]; }
  float gacc[16];
  #pragma unroll 16
  for (int i=0;i<16;i++) gacc[i]=0.f;
  float zacc = 0.f;
  for (int t = t0 + wv; t < tmax; t += 8) {
    const uint4 hv = *(const uint4*)(hp + ((size_t)b*TT + t)*HH + lane*8);
    u32 uu[4] = {hv.x, hv.y, hv.z, hv.w};
    float p = 0.f;
    #pragma unroll
    for (int q=0;q<4;q++){
      p += wa[2*q+0]*fast_tanh(bf2f((u16)(uu[q]&0xffffu))+sw[2*q+0]);
      p += wa[2*q+1]*fast_tanh(bf2f((u16)(uu[q]>>16))+sw[2*q+1]);
    }
    #pragma unroll
    for (int off=32; off; off>>=1) p += __shfl_xor(p, off, 64);
    float wgt = __expf(p);
    zacc += wgt;
    const uint4* hr = (const uint4*)(hb + ((size_t)b*TT + t)*H2 + lane*16);
    uint4 h0 = hr[0], h1 = hr[1];
    u32 hh[8] = {h0.x,h0.y,h0.z,h0.w,h1.x,h1.y,h1.z,h1.w};
    #pragma unroll
    for (int q=0;q<8;q++){
      gacc[2*q+0] += wgt*bf2f((u16)(hh[q]&0xffffu));
      gacc[2*q+1] += wgt*bf2f((u16)(hh[q]>>16));
    }
  }
  __shared__ float sg[8][H2];
  __shared__ float szz[8];
  #pragma unroll
  for (int q=0;q<4;q++)
    *(float4*)(&sg[wv][lane*16+q*4]) = make_float4(gacc[4*q],gacc[4*q+1],gacc[4*q+2],gacc[4*q+3]);
  if (lane==0) szz[wv]=zacc;
  __syncthreads();
  int e = tid*2;
  float v0=0.f, v1=0.f;
  #pragma unroll
  for (int w8=0; w8<8; w8++){ v0 += sg[w8][e]; v1 += sg[w8][e+1]; }
  *(float2*)(gpart + ((size_t)(b*8+chunk))*H2 + e) = make_float2(v0,v1);
  if (tid==0){ float z=0.f;
    #pragma unroll
    for (int w8=0;w8<8;w8++) z+=szz[w8];
    Zpart[b*8+chunk]=z; }
}

// per-step: A=g frags (built from gpart), B=WstepF -> z(tanh)->zF, rec fp32
__global__ __launch_bounds__(256) void k_step(const float* __restrict__ gpart,
  const float* __restrict__ Zpart, const u16* __restrict__ WstepF,
  const float* __restrict__ proj_sy, const float* __restrict__ proj_sr,
  const float* __restrict__ b_gy, const float* __restrict__ b_sy,
  const float* __restrict__ b_sr, const float* __restrict__ b_gr,
  const float* __restrict__ E_yr, const int* __restrict__ labels, const int lstep,
  u16* __restrict__ zF, float* __restrict__ rec)
{
  __shared__ short8 aF[32*2*64];   // 64 KiB: [kt][mt][lane]
  __shared__ float sInv[BB];
  const int tid = threadIdx.x;
  if (tid < BB){
    float z=0.f;
    #pragma unroll
    for (int c=0;c<8;c++) z += Zpart[tid*8+c];
    sInv[tid] = 1.f/z;
  }
  __syncthreads();
  for (int s=0;s<16;s++){
    int slot = tid + s*256;
    int l = slot & 63, mt = (slot>>6)&1, kt = slot>>7;
    int brow = mt*16 + (l&15);
    int kb = kt*32 + ((l>>4)<<3);
    float sum[8] = {0.f,0.f,0.f,0.f,0.f,0.f,0.f,0.f};
    #pragma unroll
    for (int c=0;c<8;c++){
      float vv[8]; ld8(gpart + ((size_t)(brow*8+c))*H2 + kb, vv);
      #pragma unroll 8
      for (int e=0;e<8;e++) sum[e] += vv[e];
    }
    float inv = sInv[brow];
    short8 v;
    #pragma unroll 8
    for (int e=0;e<8;e++) v[e] = (short)f2bf(sum[e]*inv);
    aF[(kt*2+mt)*64 + l] = v;
  }
  __syncthreads();
  const int l = tid&63, wv = tid>>6;
  f32x4 acc[2][4] = {};
  for (int kt=0; kt<32; kt++){
    short8 a0 = aF[(kt*2+0)*64 + l];
    short8 a1 = aF[(kt*2+1)*64 + l];
    #pragma unroll
    for (int j=0;j<4;j++){
      int ntg = blockIdx.x*16 + wv*4 + j;
      short8 bfr = *(const short8*)(WstepF + (((size_t)ntg*32 + kt)*64 + l)*8);
      acc[0][j] = mfma16(a0, bfr, acc[0][j]);
      acc[1][j] = mfma16(a1, bfr, acc[1][j]);
    }
  }
  #pragma unroll
  for (int j=0;j<4;j++){
    int ntg = blockIdx.x*16 + wv*4 + j;
    int n = ntg*16 + (l&15);
    #pragma unroll
    for (int mt=0;mt<2;mt++){
      #pragma unroll
      for (int r=0;r<4;r++){
        int b = mt*16 + ((l>>4)<<2) + r;
        float v = acc[mt][j][r];
        if (n < HH){
          v = fast_tanh(v + proj_sy[b*HH+n] + b_gy[n] + b_sy[n]);
          int row = b*LL + lstep;
          int mtg = row>>4, rr = row&15;
          int ktz = n>>5;
          int lp = rr | (((n>>3)&3)<<4);
          zF[(((size_t)mtg*16 + ktz)*64 + lp)*8 + (n&7)] = f2bf(v);
        } else {
          int q = n - HH;
          int tok = labels[b*LL + lstep];
          rec[b*H4 + q] = v + proj_sr[b*H4+q] + b_sr[q] + b_gr[q]
                        + E_yr[(size_t)tok*H4 + q];
        }
      }
    }
  }
}

// per-step: LSTM (redundant per block) -> s frags -> proj_att|proj_sy|proj_sr
__global__ __launch_bounds__(256) void k_proj(const float* __restrict__ rec,
  const float* __restrict__ c_in, const u16* __restrict__ WprojF,
  float* __restrict__ c_out,
  float* __restrict__ proj_att, float* __restrict__ proj_sy, float* __restrict__ proj_sr)
{
  __shared__ short8 sF[16*2*64];   // 32 KiB
  const int tid = threadIdx.x;
  for (int s=0;s<8;s++){
    int slot = tid + s*256;
    int l = slot & 63, mt = (slot>>6)&1, kt = slot>>7;
    int brow = mt*16 + (l&15);
    int kb = kt*32 + ((l>>4)<<3);
    const float* rb = rec + (size_t)brow*H4 + kb;
    float iv[8], fv[8], gv[8], ov[8], cv[8];
    ld8(rb, iv); ld8(rb+HH, fv); ld8(rb+H2, gv); ld8(rb+1536, ov);
    ld8(c_in + brow*HH + kb, cv);
    float cn[8];
    short8 v;
    #pragma unroll 8
    for (int e=0;e<8;e++){
      float ii = sigm(iv[e]), ff = sigm(fv[e]);
      float cg = fast_tanh(gv[e]), oo = sigm(ov[e]);
      cn[e] = ff*cv[e] + ii*cg;
      v[e] = (short)f2bf(oo*fast_tanh(cn[e]));
    }
    if (blockIdx.x == 0){
      float* cp = c_out + brow*HH + kb;
      *(float4*)cp     = make_float4(cn[0],cn[1],cn[2],cn[3]);
      *(float4*)(cp+4) = make_float4(cn[4],cn[5],cn[6],cn[7]);
    }
    sF[(kt*2+mt)*64 + l] = v;
  }
  __syncthreads();
  const int l = tid&63, wv = tid>>6;
  f32x4 acc[2][4] = {};
  for (int kt=0; kt<16; kt++){
    short8 a0 = sF[(kt*2+0)*64 + l];
    short8 a1 = sF[(kt*2+1)*64 + l];
    #pragma unroll
    for (int j=0;j<4;j++){
      int ntg = blockIdx.x*16 + wv*4 + j;
      short8 bfr = *(const short8*)(WprojF + (((size_t)ntg*16 + kt)*64 + l)*8);
      acc[0][j] = mfma16(a0, bfr, acc[0][j]);
      acc[1][j] = mfma16(a1, bfr, acc[1][j]);
    }
  }
  #pragma unroll
  for (int j=0;j<4;j++){
    int ntg = blockIdx.x*16 + wv*4 + j;
    int n = ntg*16 + (l&15);
    #pragma unroll
    for (int mt=0;mt<2;mt++){
      #pragma unroll
      for (int r=0;r<4;r++){
        int b = mt*16 + ((l>>4)<<2) + r;
        float v = acc[mt][j][r];
        if (n < HH)            proj_att[b*HH + n]        = v;
        else if (n < H2)       proj_sy[b*HH + (n-HH)]    = v;
        else                   proj_sr[b*H4 + (n-H2)]    = v;
      }
    }
  }
}

extern "C" void kernel_launch(void* const* d_in, const int* in_sizes, int n_in,
                              void* d_out, int out_size, void* d_ws, size_t ws_size,
                              hipStream_t stream)
{
  (void)in_sizes; (void)n_in; (void)out_size; (void)ws_size;
  const float* h       = (const float*)d_in[0];
  const int*   seq     = (const int*)d_in[1];
  const int*   labels  = (const int*)d_in[2];
  const float* W_sy    = (const float*)d_in[3];
  const float* b_sy    = (const float*)d_in[4];
  const float* W_gy    = (const float*)d_in[5];
  const float* b_gy    = (const float*)d_in[6];
  const float* W_yy    = (const float*)d_in[7];
  const float* b_yy    = (const float*)d_in[8];
  const float* E_yr    = (const float*)d_in[9];
  const float* W_sr    = (const float*)d_in[10];
  const float* b_sr    = (const float*)d_in[11];
  const float* W_gr    = (const float*)d_in[12];
  const float* b_gr    = (const float*)d_in[13];
  const float* W_s_att = (const float*)d_in[14];
  const float* W_h_att = (const float*)d_in[15];
  const float* b_att   = (const float*)d_in[16];
  const float* w_att   = (const float*)d_in[17];
  float* out = (float*)d_out;

  char* w = (char*)d_ws;
  u16* hp      = (u16*)w;  w += (size_t)BB*TT*HH*2;          // 32.77 MB
  u16* hb      = (u16*)w;  w += (size_t)BB*TT*H2*2;          // 65.54 MB
  u16* WhF     = (u16*)w;  w += (size_t)32*32*64*8*2;        // 1.05 MB
  u16* WstepF  = (u16*)w;  w += (size_t)160*32*64*8*2;       // 5.24 MB
  u16* WprojF  = (u16*)w;  w += (size_t)192*16*64*8*2;       // 3.15 MB
  u16* WyyF    = (u16*)w;  w += (size_t)640*16*64*8*2;       // 10.49 MB
  u16* zF      = (u16*)w;  w += (size_t)200*16*64*8*2;       // 3.28 MB
  float* gpart = (float*)w; w += (size_t)BB*8*H2*4;          // 1.05 MB
  float* Zpart = (float*)w; w += (size_t)BB*8*4;
  float* rec   = (float*)w; w += (size_t)BB*H4*4;
  float* zbase = (float*)w;                                   // zeroed region:
  float* proj_att = (float*)w; w += (size_t)BB*HH*4;
  float* proj_sy  = (float*)w; w += (size_t)BB*HH*4;
  float* proj_sr  = (float*)w; w += (size_t)BB*H4*4;
  float* cbuf     = (float*)w; w += (size_t)2*BB*HH*4;

  // ---- one-time preprocessing (runs every call; deterministic) ----
  k_cvt_h<<<2048,256,0,stream>>>((const float4*)h, (ushort4*)hb, BB*TT*H2/4);
  k_swz<<<256 ,256,0,stream>>>(WhF,   32,32, W_h_att,512,512, 0,0,0, 0,0,0);
  k_swz<<<1280,256,0,stream>>>(WstepF,160,32, W_gy,512,512, W_gr,2048,2048, 0,0,0);
  k_swz<<<768 ,256,0,stream>>>(WprojF,192,16, W_s_att,512,512, W_sy,512,512, W_sr,2048,2048);
  k_swz<<<2560,256,0,stream>>>(WyyF, 640,16, W_yy,10000,10000, 0,0,0, 0,0,0);
  k_zero<<<128,256,0,stream>>>((float4*)zbase);  // proj_* + cbuf = 131072 floats
  k_hproj<<<dim3(250,4),256,0,stream>>>(h, WhF, b_att, hp);

  for (int l=0;l<LL;l++){
    k_flash<<<dim3(8,BB),512,0,stream>>>(hp, hb, proj_att, w_att, seq, gpart, Zpart);
    k_step<<<10,256,0,stream>>>(gpart, Zpart, WstepF, proj_sy, proj_sr,
                                b_gy, b_sy, b_sr, b_gr, E_yr, labels, l, zF, rec);
    const float* c_in  = cbuf + (size_t)(l&1)*BB*HH;
    float*       c_out = cbuf + (size_t)((l+1)&1)*BB*HH;
    k_proj<<<12,256,0,stream>>>(rec, c_in, WprojF, c_out,
                                proj_att, proj_sy, proj_sr);
  }
  k_ybig<<<dim3(25,80),256,0,stream>>>(zF, WyyF, b_yy, out);
}